// Round 10
// baseline (456.729 us; speedup 1.0000x reference)
//
#include <hip/hip_runtime.h>
#include <hip/hip_bf16.h>
#include <hip/hip_cooperative_groups.h>

namespace cg = cooperative_groups;

// Round 14: SINGLE COOPERATIVE LAUNCH (3 dispatches -> 1).
//   Ledger (R10-R13, bench-verified): attn ~115us, qkv ~15-18us, cvtw ~2-5us,
//   per-launch overhead ~20-23us x3 = 60-70us of the 204.8 best total.
//   Kernel content is already tuned; the dominant remaining cost is dispatch
//   overhead -> eliminate it with hipLaunchCooperativeKernel + grid.sync().
//   Phase 0: cvtw (Wq -> bf16 pre-swizzled into d_out; first 24576 threads).
//   Phase 1: qkv -- R9-verified 512-thr structure (m-tile 128, A cvt-staged,
//            B via gl_lds from Wqbf, 6 n-tiles of 128 cols).
//   Phase 2: attn + fused proj -- R10 verbatim (114.5us, VGPR 88).
//   Between phases: __threadfence() + grid.sync() + __threadfence()
//   (release wbL2 / acquire invL2 -- cross-XCD visibility incl. stale lines
//   cached by THIS XCD during the previous bench iteration).
// ws (ushort): Q[0], K[NE], Vt[2NE], NE=16*2048*256. Wqbf in d_out (384KB,
// read in phase 1, overwritten by phase 2's out stores after grid.sync).

typedef short bf16x8 __attribute__((ext_vector_type(8)));
typedef float f32x4 __attribute__((ext_vector_type(4)));

#define MFMA16(a, b, c) __builtin_amdgcn_mfma_f32_16x16x32_bf16((a), (b), (c), 0, 0, 0)

__device__ __forceinline__ unsigned short f2bf(float f) {
  unsigned int x;
  __builtin_memcpy(&x, &f, 4);
  x = x + 0x7fffu + ((x >> 16) & 1u);
  return (unsigned short)(x >> 16);
}
__device__ __forceinline__ unsigned int pack2(float a, float b) {
  float2 t;
  t.x = a;
  t.y = b;
  __hip_bfloat162 h = __float22bfloat162_rn(t);
  unsigned int u;
  __builtin_memcpy(&u, &h, 4);
  return u;
}

// async 16B global->LDS. LDS dest is wave-uniform base + lane*16 (HW rule).
typedef __attribute__((address_space(3))) void as3_void;
typedef __attribute__((address_space(1))) const void as1_void;
__device__ __forceinline__ void gl_lds16(const void* g, void* l) {
  __builtin_amdgcn_global_load_lds((as1_void*)(unsigned long long)g,
                                   (as3_void*)(unsigned int)(unsigned long long)l,
                                   16, 0, 0);
}

__global__ __launch_bounds__(512, 2) void fused_kernel(
    const float* __restrict__ X, const float* __restrict__ Wq,
    const float* __restrict__ Wo, const float* __restrict__ bias,
    unsigned short* __restrict__ Qb, unsigned short* __restrict__ Kb,
    unsigned short* __restrict__ Vt, unsigned short* __restrict__ Wqbf,
    float* __restrict__ out) {
  __shared__ __attribute__((aligned(16))) unsigned short smem[65536];  // 131072 B
  cg::grid_group grid = cg::this_grid();

  const int t = threadIdx.x;
  const int w = t >> 6, lane = t & 63, lo = lane & 15, quad = lane >> 4;

  // ================= phase 0: cvtw (Wq fp32 -> bf16, pre-swizzled) =========
  {
    int idx = blockIdx.x * 512 + t;  // need 24576 of 131072 threads
    if (idx < 24576) {
      int row = idx >> 5, sc = idx & 31;
      int c = (sc & 24) | ((sc ^ (row & 7)) & 7);
      const float* wp = Wq + (size_t)row * 256 + c * 8;
      float4 a0 = *(const float4*)wp, a1 = *(const float4*)(wp + 4);
      uint4 u;
      u.x = pack2(a0.x, a0.y);
      u.y = pack2(a0.z, a0.w);
      u.z = pack2(a1.x, a1.y);
      u.w = pack2(a1.z, a1.w);
      *(uint4*)(Wqbf + (size_t)idx * 8) = u;
    }
  }
  __threadfence();
  grid.sync();
  __threadfence();

  // ================= phase 1: QKV GEMM (R9-verified 512-thr) ===============
  // m-tile 128 rows; A (X) cvt-staged to Al once; 6 n-tiles of 128 cols via
  // gl_lds from Wqbf. Wave w -> (wr=(w>>2)*64, wc=(w&3)*32), acc[4][2].
  {
    unsigned short* Al = smem;          // 64KB
    unsigned short* Bl = smem + 32768;  // 64KB
    const int m0 = blockIdx.x * 128;
    const int wr = (w >> 2) * 64, wc = (w & 3) * 32;

#pragma unroll
    for (int r = 0; r < 8; ++r) {
      int ci = r * 512 + t;
      int row = ci >> 5, c = ci & 31;
      int s = (c & 24) | ((c ^ (row & 7)) & 7);
      const float* xp = X + (size_t)(m0 + row) * 256 + c * 8;
      float4 a0 = *(const float4*)xp, a1 = *(const float4*)(xp + 4);
      uint4 ua;
      ua.x = pack2(a0.x, a0.y);
      ua.y = pack2(a0.z, a0.w);
      ua.z = pack2(a1.x, a1.y);
      ua.w = pack2(a1.z, a1.w);
      *(uint4*)(&Al[row * 256 + s * 8]) = ua;
    }

    for (int n = 0; n < 6; ++n) {
      const int n0 = n * 128;
      if (n > 0) __syncthreads();  // prev compute done before overwriting Bl
      {
        const unsigned short* Wb = Wqbf + (size_t)n0 * 256;
        int lofs = __builtin_amdgcn_readfirstlane(w * 64 * 8);
#pragma unroll
        for (int r = 0; r < 8; ++r)
          gl_lds16(Wb + (size_t)(r * 512 + t) * 8, &Bl[r * 512 * 8 + lofs]);
      }
      asm volatile("s_waitcnt vmcnt(0)" ::: "memory");
      __syncthreads();

      f32x4 zero4 = {0.f, 0.f, 0.f, 0.f};
      f32x4 acc[4][2];
#pragma unroll
      for (int i = 0; i < 4; i++)
#pragma unroll
        for (int j = 0; j < 2; j++) acc[i][j] = zero4;

#pragma unroll
      for (int kc = 0; kc < 8; ++kc) {
        const int c = kc * 4 + quad;
        const int jj = (c & 24) | ((c ^ (lo & 7)) & 7);
        bf16x8 af[4], bfr[2];
#pragma unroll
        for (int mt = 0; mt < 4; ++mt)
          af[mt] = *(const bf16x8*)(&Al[(wr + mt * 16 + lo) * 256 + jj * 8]);
#pragma unroll
        for (int nt = 0; nt < 2; ++nt)
          bfr[nt] = *(const bf16x8*)(&Bl[(wc + nt * 16 + lo) * 256 + jj * 8]);
#pragma unroll
        for (int mt = 0; mt < 4; ++mt)
#pragma unroll
          for (int nt = 0; nt < 2; ++nt)
            acc[mt][nt] = MFMA16(af[mt], bfr[nt], acc[mt][nt]);
      }

      const int mb = m0 + wr, nb = n0 + wc;
      if (n0 < 256) {
#pragma unroll
        for (int mt = 0; mt < 4; ++mt)
#pragma unroll
          for (int nt = 0; nt < 2; ++nt) {
            int m = mb + mt * 16 + quad * 4;
            int nn = nb + nt * 16 + lo;
            unsigned short* p = Qb + (size_t)m * 256 + nn;
            p[0] = f2bf(acc[mt][nt][0]);
            p[256] = f2bf(acc[mt][nt][1]);
            p[512] = f2bf(acc[mt][nt][2]);
            p[768] = f2bf(acc[mt][nt][3]);
          }
      } else if (n0 < 512) {
#pragma unroll
        for (int mt = 0; mt < 4; ++mt)
#pragma unroll
          for (int nt = 0; nt < 2; ++nt) {
            int m = mb + mt * 16 + quad * 4;
            int nn = nb + nt * 16 + lo - 256;
            unsigned short* p = Kb + (size_t)m * 256 + nn;
            p[0] = f2bf(acc[mt][nt][0]);
            p[256] = f2bf(acc[mt][nt][1]);
            p[512] = f2bf(acc[mt][nt][2]);
            p[768] = f2bf(acc[mt][nt][3]);
          }
      } else {
#pragma unroll
        for (int mt = 0; mt < 4; ++mt)
#pragma unroll
          for (int nt = 0; nt < 2; ++nt) {
            int m = mb + mt * 16 + quad * 4;
            int d = nb + nt * 16 + lo - 512;
            int b = m >> 11, s = m & 2047;
            uint2 v;
            v.x = pack2(acc[mt][nt][0], acc[mt][nt][1]);
            v.y = pack2(acc[mt][nt][2], acc[mt][nt][3]);
            *(uint2*)(Vt + ((size_t)(b * 256 + d)) * 2048 + s) = v;
          }
      }
    }
  }
  __threadfence();
  grid.sync();
  __threadfence();

  // ================= phase 2: attn + fused proj (R10 verbatim) =============
  {
    const int id = blockIdx.x;
    const int b = id & 15;
    const int qt = id >> 4;
    constexpr float SCALE_LOG2E = 0.0625f * 1.4426950408889634f;

    const unsigned short* Kbb = Kb + (size_t)b * 2048 * 256;
    const unsigned short* Vb = Vt + (size_t)b * 256 * 2048;

    unsigned int gkoff[4], gvoff[4];
    int loK[4], loV[4];
#pragma unroll
    for (int r = 0; r < 4; ++r) {
      int ck = r * 512 + t;
      int row = ck >> 5, j = ck & 31;
      int srcj = (j & 16) | ((j ^ (row & 15)) & 15);
      gkoff[r] = (unsigned int)((row * 256 + srcj * 8) * 2);
      loK[r] = __builtin_amdgcn_readfirstlane((r * 512 + w * 64) * 8);

      int cv = r * 512 + t;
      int d = cv >> 3, slot = cv & 7;
      int g = slot ^ (d & 7);
      gvoff[r] = (unsigned int)((d * 2048 + g * 8) * 2);
      loV[r] = __builtin_amdgcn_readfirstlane(16384 + (r * 512 + w * 64) * 8);
    }

    const int qrow = b * 2048 + qt * 128 + w * 16 + lo;
    const unsigned short* qp = Qb + (size_t)qrow * 256;
    bf16x8 qf[8];
#pragma unroll
    for (int ks = 0; ks < 8; ++ks)
      qf[ks] = *(const bf16x8*)(qp + ks * 32 + quad * 8);

    f32x4 zero4 = {0.f, 0.f, 0.f, 0.f};
    f32x4 oacc[16];
#pragma unroll
    for (int i = 0; i < 16; i++) oacc[i] = zero4;
    float m_run = -1e30f, l_run = 0.f;

#pragma unroll
    for (int r = 0; r < 4; ++r) {
      gl_lds16((const char*)Kbb + gkoff[r], &smem[loK[r]]);
      gkoff[r] += 64 * 256 * 2;
    }
#pragma unroll
    for (int r = 0; r < 4; ++r) {
      gl_lds16((const char*)Vb + gvoff[r], &smem[loV[r]]);
      gvoff[r] += 64 * 2;
    }

    for (int it = 0; it < 32; ++it) {
      asm volatile("s_waitcnt vmcnt(0)" ::: "memory");
      __syncthreads();
      if (it < 31) {
        const int pn = ((it + 1) & 1) * 32768;
#pragma unroll
        for (int r = 0; r < 4; ++r) {
          gl_lds16((const char*)Kbb + gkoff[r], &smem[pn + loK[r]]);
          gkoff[r] += 64 * 256 * 2;
        }
#pragma unroll
        for (int r = 0; r < 4; ++r) {
          gl_lds16((const char*)Vb + gvoff[r], &smem[pn + loV[r]]);
          gvoff[r] += 64 * 2;
        }
      }
      const unsigned short* Kl = smem + (it & 1) * 32768;
      const unsigned short* Vl = Kl + 16384;

      f32x4 sacc[4];
#pragma unroll
      for (int r = 0; r < 4; ++r) sacc[r] = zero4;
      __builtin_amdgcn_s_setprio(1);
#pragma unroll
      for (int ks = 0; ks < 8; ++ks) {
        const int c = ks * 4 + quad;
        const int jj = (c & 16) | ((c ^ lo) & 15);
#pragma unroll
        for (int r = 0; r < 4; ++r) {
          bf16x8 kf = *(const bf16x8*)(&Kl[(r * 16 + lo) * 256 + jj * 8]);
          sacc[r] = MFMA16(kf, qf[ks], sacc[r]);
        }
      }
      __builtin_amdgcn_s_setprio(0);

      float p[4][4];
      float cmax = -1e30f;
#pragma unroll
      for (int r = 0; r < 4; r++)
#pragma unroll
        for (int i = 0; i < 4; i++) {
          p[r][i] = sacc[r][i] * SCALE_LOG2E;
          cmax = fmaxf(cmax, p[r][i]);
        }
      cmax = fmaxf(cmax, __shfl_xor(cmax, 16));
      cmax = fmaxf(cmax, __shfl_xor(cmax, 32));
      if (!__all(cmax <= m_run + 8.f)) {
        float mnew = fmaxf(m_run, cmax);
        float alpha = exp2f(m_run - mnew);
        l_run *= alpha;
#pragma unroll
        for (int i = 0; i < 16; i++) oacc[i] *= alpha;
        m_run = mnew;
      }
      float rsum = 0.f;
#pragma unroll
      for (int r = 0; r < 4; r++)
#pragma unroll
        for (int i = 0; i < 4; i++) {
          p[r][i] = exp2f(p[r][i] - m_run);
          rsum += p[r][i];
        }
      rsum += __shfl_xor(rsum, 16);
      rsum += __shfl_xor(rsum, 32);
      l_run += rsum;

      unsigned int pk[4][2];
#pragma unroll
      for (int r = 0; r < 4; r++) {
        pk[r][0] = pack2(p[r][0], p[r][1]);
        pk[r][1] = pack2(p[r][2], p[r][3]);
      }

#pragma unroll
      for (int ks2 = 0; ks2 < 2; ++ks2) {
        union {
          unsigned int u[4];
          bf16x8 v;
        } cvt;
#pragma unroll
        for (int dd = 0; dd < 4; ++dd) {
          int src = lo + 16 * ((2 * quad + (dd >> 1)) & 3);
          unsigned int v0 = (unsigned int)__shfl((int)pk[2 * ks2][dd & 1], src);
          unsigned int v1 = (unsigned int)__shfl((int)pk[2 * ks2 + 1][dd & 1], src);
          cvt.u[dd] = (quad >> 1) ? v1 : v0;
        }
        bf16x8 pf = cvt.v;
        __builtin_amdgcn_s_setprio(1);
#pragma unroll
        for (int dt = 0; dt < 16; ++dt) {
          int slot = (ks2 * 4 + quad) ^ (lo & 7);
          bf16x8 vf = *(const bf16x8*)(&Vl[(dt * 16 + lo) * 64 + slot * 8]);
          oacc[dt] = MFMA16(vf, pf, oacc[dt]);
        }
        __builtin_amdgcn_s_setprio(0);
      }
    }

    // ---- fused output projection ----
    float inv = 1.0f / l_run;
    uint2 c2[16];
#pragma unroll
    for (int dt = 0; dt < 16; ++dt) {
      c2[dt].x = pack2(oacc[dt][0] * inv, oacc[dt][1] * inv);
      c2[dt].y = pack2(oacc[dt][2] * inv, oacc[dt][3] * inv);
    }

    __syncthreads();
#pragma unroll
    for (int r = 0; r < 16; ++r) {
      int ci = r * 512 + t;
      int row = ci >> 5, c = ci & 31;
      int s = (c & 24) | ((c ^ (row & 7)) & 7);
      const float* wp = Wo + (size_t)row * 256 + c * 8;
      float4 a0 = *(const float4*)wp, a1 = *(const float4*)(wp + 4);
      uint4 ua;
      ua.x = pack2(a0.x, a0.y);
      ua.y = pack2(a0.z, a0.w);
      ua.z = pack2(a1.x, a1.y);
      ua.w = pack2(a1.z, a1.w);
      *(uint4*)(&smem[row * 256 + s * 8]) = ua;
    }
    __syncthreads();

    f32x4 outacc[16];
#pragma unroll
    for (int i = 0; i < 16; i++) outacc[i] = zero4;

#pragma unroll
    for (int ks = 0; ks < 8; ++ks) {
      int sa = lo + 16 * ((quad & 1) * 2);
      unsigned int xA = (unsigned int)__shfl((int)c2[2 * ks].x, sa);
      unsigned int yA = (unsigned int)__shfl((int)c2[2 * ks].y, sa);
      unsigned int xB = (unsigned int)__shfl((int)c2[2 * ks].x, sa + 16);
      unsigned int yB = (unsigned int)__shfl((int)c2[2 * ks].y, sa + 16);
      unsigned int xA1 = (unsigned int)__shfl((int)c2[2 * ks + 1].x, sa);
      unsigned int yA1 = (unsigned int)__shfl((int)c2[2 * ks + 1].y, sa);
      unsigned int xB1 = (unsigned int)__shfl((int)c2[2 * ks + 1].x, sa + 16);
      unsigned int yB1 = (unsigned int)__shfl((int)c2[2 * ks + 1].y, sa + 16);
      union {
        unsigned int u[4];
        bf16x8 v;
      } cvt;
      bool hiq = (quad >> 1) != 0;
      cvt.u[0] = hiq ? xA1 : xA;
      cvt.u[1] = hiq ? yA1 : yA;
      cvt.u[2] = hiq ? xB1 : xB;
      cvt.u[3] = hiq ? yB1 : yB;
      bf16x8 pf = cvt.v;

      const int c = ks * 4 + quad;
      const int jj = (c & 24) | ((c ^ (lo & 7)) & 7);
      __builtin_amdgcn_s_setprio(1);
#pragma unroll
      for (int et = 0; et < 16; ++et) {
        bf16x8 af = *(const bf16x8*)(&smem[(et * 16 + lo) * 256 + jj * 8]);
        outacc[et] = MFMA16(af, pf, outacc[et]);
      }
      __builtin_amdgcn_s_setprio(0);
    }

    float* op = out + (size_t)qrow * 256;
#pragma unroll
    for (int et = 0; et < 16; ++et) {
      const float4 b4 = *(const float4*)(bias + et * 16 + quad * 4);
      float4 v;
      v.x = outacc[et][0] + b4.x;
      v.y = outacc[et][1] + b4.y;
      v.z = outacc[et][2] + b4.z;
      v.w = outacc[et][3] + b4.w;
      *(float4*)(op + et * 16 + quad * 4) = v;
    }
  }
}

extern "C" void kernel_launch(void* const* d_in, const int* in_sizes, int n_in,
                              void* d_out, int out_size, void* d_ws, size_t ws_size,
                              hipStream_t stream) {
  const float* X = (const float*)d_in[0];
  const float* Wq = (const float*)d_in[1];
  const float* Wo = (const float*)d_in[2];
  const float* Bo = (const float*)d_in[3];
  float* out = (float*)d_out;
  unsigned short* ws = (unsigned short*)d_ws;

  const size_t NE = (size_t)16 * 2048 * 256;
  unsigned short* Qb = ws;
  unsigned short* Kb = ws + NE;
  unsigned short* Vt = ws + 2 * NE;
  unsigned short* Wqbf = (unsigned short*)d_out;  // read in phase 1; phase 2
                                                  // overwrites with final out

  void* args[] = {(void*)&X,  (void*)&Wq, (void*)&Wo,   (void*)&Bo, (void*)&Qb,
                  (void*)&Kb, (void*)&Vt, (void*)&Wqbf, (void*)&out};
  hipLaunchCooperativeKernel((const void*)fused_kernel, dim3(256), dim3(512),
                             args, 0, stream);
}

// Round 11
// 208.961 us; speedup vs baseline: 2.1857x; 2.1857x over previous
//
#include <hip/hip_runtime.h>
#include <hip/hip_bf16.h>

// Round 15: REVERT to best-verified configuration (R10 arrangement, 204.8us).
//   R14's cooperative single-launch ran 2.9x slower per unit work (coop block
//   placement breaks the b=id&15 -> XCD L2 mapping; 1-blk/CU + vmcnt(0)/iter
//   exposes the resulting L3 latency). Banking the known-good build:
//   k0 cvtw: Wq fp32 -> bf16, pre-swizzled, into d_out (dead until attn).
//   k1 qkv: R11-verified: 2 blk/CU, A-frags hoisted to regs, gl_lds B-staging
//           from Wqbf, swapped-operand Q/K epilogue (wide uint2 stores).
//   k2 attn: R10-verified: BN=64 K+V LDS double-buffer, T13 defer-rescale,
//           setprio, fused output projection (proj GEMM hides in epilogue).
// ws (ushort): Q[0], K[NE], Vt[2NE], NE=16*2048*256. Wqbf in d_out (384KB).

typedef short bf16x8 __attribute__((ext_vector_type(8)));
typedef float f32x4 __attribute__((ext_vector_type(4)));

#define MFMA16(a, b, c) __builtin_amdgcn_mfma_f32_16x16x32_bf16((a), (b), (c), 0, 0, 0)

__device__ __forceinline__ unsigned short f2bf(float f) {
  unsigned int x;
  __builtin_memcpy(&x, &f, 4);
  x = x + 0x7fffu + ((x >> 16) & 1u);
  return (unsigned short)(x >> 16);
}
__device__ __forceinline__ unsigned int pack2(float a, float b) {
  float2 t;
  t.x = a;
  t.y = b;
  __hip_bfloat162 h = __float22bfloat162_rn(t);
  unsigned int u;
  __builtin_memcpy(&u, &h, 4);
  return u;
}

// async 16B global->LDS. LDS dest is wave-uniform base + lane*16 (HW rule).
typedef __attribute__((address_space(3))) void as3_void;
typedef __attribute__((address_space(1))) const void as1_void;
__device__ __forceinline__ void gl_lds16(const void* g, void* l) {
  __builtin_amdgcn_global_load_lds((as1_void*)(unsigned long long)g,
                                   (as3_void*)(unsigned int)(unsigned long long)l,
                                   16, 0, 0);
}

// ---------------- W_qkv pre-convert (fp32 -> bf16, pre-swizzled) ----------------
__global__ __launch_bounds__(256, 4) void cvtw_kernel(
    const float* __restrict__ W, unsigned short* __restrict__ Wbf) {
  int idx = blockIdx.x * 256 + threadIdx.x;
  int row = idx >> 5, sc = idx & 31;
  int c = (sc & 24) | ((sc ^ (row & 7)) & 7);
  const float* wp = W + (size_t)row * 256 + c * 8;
  float4 a0 = *(const float4*)wp, a1 = *(const float4*)(wp + 4);
  uint4 u;
  u.x = pack2(a0.x, a0.y);
  u.y = pack2(a0.z, a0.w);
  u.z = pack2(a1.x, a1.y);
  u.w = pack2(a1.z, a1.w);
  *(uint4*)(Wbf + (size_t)idx * 8) = u;
}

// ---------------- QKV GEMM (R11-verified) ----------------
// grid(512), block 256 (4 waves), 2 blocks/CU (64KB LDS). m-tile 64 rows.
// A staged to LDS once then hoisted to af2[2][8] regs; 12 n-tiles of 64 cols,
// B via gl_lds from pre-swizzled Wqbf. Wave w -> (wr=(w>>1)*32, wc=(w&1)*32).
__global__ __launch_bounds__(256, 2) void qkv_kernel(
    const float* __restrict__ X, const unsigned short* __restrict__ Wqbf,
    unsigned short* __restrict__ Q, unsigned short* __restrict__ Kp,
    unsigned short* __restrict__ Vt) {
  __shared__ unsigned short Al[64 * 256];  // 32KB
  __shared__ unsigned short Bl[64 * 256];  // 32KB
  const int m0 = blockIdx.x * 64;
  const int t = threadIdx.x;
  const int w = t >> 6, lane = t & 63, lo = lane & 15, quad = lane >> 4;
  const int wr = (w >> 1) * 32, wc = (w & 1) * 32;

#pragma unroll
  for (int r = 0; r < 8; ++r) {
    int ci = r * 256 + t;
    int row = ci >> 5, c = ci & 31;
    int s = (c & 24) | ((c ^ (row & 7)) & 7);
    const float* xp = X + (size_t)(m0 + row) * 256 + c * 8;
    float4 a0 = *(const float4*)xp, a1 = *(const float4*)(xp + 4);
    uint4 ua;
    ua.x = pack2(a0.x, a0.y);
    ua.y = pack2(a0.z, a0.w);
    ua.z = pack2(a1.x, a1.y);
    ua.w = pack2(a1.z, a1.w);
    *(uint4*)(&Al[row * 256 + s * 8]) = ua;
  }
  __syncthreads();

  // hoist A fragments to registers: af2[mt][kc] (64 VGPR), LDS read once
  bf16x8 af2[2][8];
#pragma unroll
  for (int kc = 0; kc < 8; ++kc) {
    const int c = kc * 4 + quad;
    const int jj = (c & 24) | ((c ^ (lo & 7)) & 7);
#pragma unroll
    for (int mt = 0; mt < 2; ++mt)
      af2[mt][kc] = *(const bf16x8*)(&Al[(wr + mt * 16 + lo) * 256 + jj * 8]);
  }

  const int lofs = __builtin_amdgcn_readfirstlane(w * 64 * 8);
  for (int n = 0; n < 12; ++n) {
    const int n0 = n * 64;
    __syncthreads();  // prev compute done before overwriting Bl
    {
      const unsigned short* Wb = Wqbf + (size_t)n0 * 256;
#pragma unroll
      for (int r = 0; r < 8; ++r)
        gl_lds16(Wb + (size_t)(r * 256 + t) * 8, &Bl[r * 256 * 8 + lofs]);
    }
    asm volatile("s_waitcnt vmcnt(0)" ::: "memory");
    __syncthreads();

    f32x4 zero4 = {0.f, 0.f, 0.f, 0.f};
    f32x4 acc[2][2];
#pragma unroll
    for (int i = 0; i < 2; i++)
#pragma unroll
      for (int j = 0; j < 2; j++) acc[i][j] = zero4;

    if (n0 < 512) {
      // Q/K: swapped operands -> C[row=nn-local][col=m-local]
#pragma unroll
      for (int kc = 0; kc < 8; ++kc) {
        const int c = kc * 4 + quad;
        const int jj = (c & 24) | ((c ^ (lo & 7)) & 7);
        bf16x8 bfr[2];
#pragma unroll
        for (int nt = 0; nt < 2; ++nt)
          bfr[nt] = *(const bf16x8*)(&Bl[(wc + nt * 16 + lo) * 256 + jj * 8]);
#pragma unroll
        for (int mt = 0; mt < 2; ++mt)
#pragma unroll
          for (int nt = 0; nt < 2; ++nt)
            acc[mt][nt] = MFMA16(bfr[nt], af2[mt][kc], acc[mt][nt]);
      }
      unsigned short* dst = (n0 < 256) ? Q : Kp;
      const int nbase = (n0 < 256) ? n0 : n0 - 256;
#pragma unroll
      for (int mt = 0; mt < 2; ++mt)
#pragma unroll
        for (int nt = 0; nt < 2; ++nt) {
          int m = m0 + wr + mt * 16 + lo;
          int nn = nbase + wc + nt * 16 + quad * 4;
          uint2 v;
          v.x = pack2(acc[mt][nt][0], acc[mt][nt][1]);
          v.y = pack2(acc[mt][nt][2], acc[mt][nt][3]);
          *(uint2*)(dst + (size_t)m * 256 + nn) = v;
        }
    } else {
      // V: original order -> C[row=m-local][col=d-local], uint2 over s
#pragma unroll
      for (int kc = 0; kc < 8; ++kc) {
        const int c = kc * 4 + quad;
        const int jj = (c & 24) | ((c ^ (lo & 7)) & 7);
        bf16x8 bfr[2];
#pragma unroll
        for (int nt = 0; nt < 2; ++nt)
          bfr[nt] = *(const bf16x8*)(&Bl[(wc + nt * 16 + lo) * 256 + jj * 8]);
#pragma unroll
        for (int mt = 0; mt < 2; ++mt)
#pragma unroll
          for (int nt = 0; nt < 2; ++nt)
            acc[mt][nt] = MFMA16(af2[mt][kc], bfr[nt], acc[mt][nt]);
      }
#pragma unroll
      for (int mt = 0; mt < 2; ++mt)
#pragma unroll
        for (int nt = 0; nt < 2; ++nt) {
          int m = m0 + wr + mt * 16 + quad * 4;
          int d = n0 + wc + nt * 16 + lo - 512;
          int b = m >> 11, s = m & 2047;
          uint2 v;
          v.x = pack2(acc[mt][nt][0], acc[mt][nt][1]);
          v.y = pack2(acc[mt][nt][2], acc[mt][nt][3]);
          *(uint2*)(Vt + ((size_t)(b * 256 + d)) * 2048 + s) = v;
        }
    }
  }
}

// ---------------- Flash attention + FUSED output projection (R10-verified) ----
// grid(256) = 16 b x 16 qt, 1 block/CU. block 512 = 8 waves. BN=64, 32 iters.
// LDS buf p in {0,1} (32768 ushorts): [K 64x256 | V^T 256x64], gl_lds src-XOR.
__global__ __launch_bounds__(512, 2) void attn_kernel(
    const unsigned short* __restrict__ Q, const unsigned short* __restrict__ K,
    const unsigned short* __restrict__ Vt, const float* __restrict__ Wo,
    const float* __restrict__ bias, float* __restrict__ out) {
  __shared__ __attribute__((aligned(16))) unsigned short smem[65536];  // 131072 B
  const int id = blockIdx.x;
  const int b = id & 15;
  const int qt = id >> 4;
  const int t = threadIdx.x;
  const int w = t >> 6, lane = t & 63, lo = lane & 15, quad = lane >> 4;
  constexpr float SCALE_LOG2E = 0.0625f * 1.4426950408889634f;

  const unsigned short* Kb = K + (size_t)b * 2048 * 256;
  const unsigned short* Vb = Vt + (size_t)b * 256 * 2048;

  unsigned int gkoff[4], gvoff[4];
  int loK[4], loV[4];
#pragma unroll
  for (int r = 0; r < 4; ++r) {
    int ck = r * 512 + t;
    int row = ck >> 5, j = ck & 31;
    int srcj = (j & 16) | ((j ^ (row & 15)) & 15);
    gkoff[r] = (unsigned int)((row * 256 + srcj * 8) * 2);
    loK[r] = __builtin_amdgcn_readfirstlane((r * 512 + w * 64) * 8);

    int cv = r * 512 + t;
    int d = cv >> 3, slot = cv & 7;
    int g = slot ^ (d & 7);
    gvoff[r] = (unsigned int)((d * 2048 + g * 8) * 2);
    loV[r] = __builtin_amdgcn_readfirstlane(16384 + (r * 512 + w * 64) * 8);
  }

  const int qrow = b * 2048 + qt * 128 + w * 16 + lo;
  const unsigned short* qp = Q + (size_t)qrow * 256;
  bf16x8 qf[8];
#pragma unroll
  for (int ks = 0; ks < 8; ++ks)
    qf[ks] = *(const bf16x8*)(qp + ks * 32 + quad * 8);

  f32x4 zero4 = {0.f, 0.f, 0.f, 0.f};
  f32x4 oacc[16];
#pragma unroll
  for (int i = 0; i < 16; i++) oacc[i] = zero4;
  float m_run = -1e30f, l_run = 0.f;

#pragma unroll
  for (int r = 0; r < 4; ++r) {
    gl_lds16((const char*)Kb + gkoff[r], &smem[loK[r]]);
    gkoff[r] += 64 * 256 * 2;
  }
#pragma unroll
  for (int r = 0; r < 4; ++r) {
    gl_lds16((const char*)Vb + gvoff[r], &smem[loV[r]]);
    gvoff[r] += 64 * 2;
  }

  for (int it = 0; it < 32; ++it) {
    asm volatile("s_waitcnt vmcnt(0)" ::: "memory");
    __syncthreads();
    if (it < 31) {
      const int pn = ((it + 1) & 1) * 32768;
#pragma unroll
      for (int r = 0; r < 4; ++r) {
        gl_lds16((const char*)Kb + gkoff[r], &smem[pn + loK[r]]);
        gkoff[r] += 64 * 256 * 2;
      }
#pragma unroll
      for (int r = 0; r < 4; ++r) {
        gl_lds16((const char*)Vb + gvoff[r], &smem[pn + loV[r]]);
        gvoff[r] += 64 * 2;
      }
    }
    const unsigned short* Kl = smem + (it & 1) * 32768;
    const unsigned short* Vl = Kl + 16384;

    f32x4 sacc[4];
#pragma unroll
    for (int r = 0; r < 4; ++r) sacc[r] = zero4;
    __builtin_amdgcn_s_setprio(1);
#pragma unroll
    for (int ks = 0; ks < 8; ++ks) {
      const int c = ks * 4 + quad;
      const int jj = (c & 16) | ((c ^ lo) & 15);
#pragma unroll
      for (int r = 0; r < 4; ++r) {
        bf16x8 kf = *(const bf16x8*)(&Kl[(r * 16 + lo) * 256 + jj * 8]);
        sacc[r] = MFMA16(kf, qf[ks], sacc[r]);
      }
    }
    __builtin_amdgcn_s_setprio(0);

    float p[4][4];
    float cmax = -1e30f;
#pragma unroll
    for (int r = 0; r < 4; r++)
#pragma unroll
      for (int i = 0; i < 4; i++) {
        p[r][i] = sacc[r][i] * SCALE_LOG2E;
        cmax = fmaxf(cmax, p[r][i]);
      }
    cmax = fmaxf(cmax, __shfl_xor(cmax, 16));
    cmax = fmaxf(cmax, __shfl_xor(cmax, 32));
    if (!__all(cmax <= m_run + 8.f)) {
      float mnew = fmaxf(m_run, cmax);
      float alpha = exp2f(m_run - mnew);
      l_run *= alpha;
#pragma unroll
      for (int i = 0; i < 16; i++) oacc[i] *= alpha;
      m_run = mnew;
    }
    float rsum = 0.f;
#pragma unroll
    for (int r = 0; r < 4; r++)
#pragma unroll
      for (int i = 0; i < 4; i++) {
        p[r][i] = exp2f(p[r][i] - m_run);
        rsum += p[r][i];
      }
    rsum += __shfl_xor(rsum, 16);
    rsum += __shfl_xor(rsum, 32);
    l_run += rsum;

    unsigned int pk[4][2];
#pragma unroll
    for (int r = 0; r < 4; r++) {
      pk[r][0] = pack2(p[r][0], p[r][1]);
      pk[r][1] = pack2(p[r][2], p[r][3]);
    }

#pragma unroll
    for (int ks2 = 0; ks2 < 2; ++ks2) {
      union {
        unsigned int u[4];
        bf16x8 v;
      } cvt;
#pragma unroll
      for (int dd = 0; dd < 4; ++dd) {
        int src = lo + 16 * ((2 * quad + (dd >> 1)) & 3);
        unsigned int v0 = (unsigned int)__shfl((int)pk[2 * ks2][dd & 1], src);
        unsigned int v1 = (unsigned int)__shfl((int)pk[2 * ks2 + 1][dd & 1], src);
        cvt.u[dd] = (quad >> 1) ? v1 : v0;
      }
      bf16x8 pf = cvt.v;
      __builtin_amdgcn_s_setprio(1);
#pragma unroll
      for (int dt = 0; dt < 16; ++dt) {
        int slot = (ks2 * 4 + quad) ^ (lo & 7);
        bf16x8 vf = *(const bf16x8*)(&Vl[(dt * 16 + lo) * 64 + slot * 8]);
        oacc[dt] = MFMA16(vf, pf, oacc[dt]);
      }
      __builtin_amdgcn_s_setprio(0);
    }
  }

  // ================= fused output projection =================
  float inv = 1.0f / l_run;
  uint2 c2[16];
#pragma unroll
  for (int dt = 0; dt < 16; ++dt) {
    c2[dt].x = pack2(oacc[dt][0] * inv, oacc[dt][1] * inv);
    c2[dt].y = pack2(oacc[dt][2] * inv, oacc[dt][3] * inv);
  }

  __syncthreads();
#pragma unroll
  for (int r = 0; r < 16; ++r) {
    int ci = r * 512 + t;
    int row = ci >> 5, c = ci & 31;
    int s = (c & 24) | ((c ^ (row & 7)) & 7);
    const float* wp = Wo + (size_t)row * 256 + c * 8;
    float4 a0 = *(const float4*)wp, a1 = *(const float4*)(wp + 4);
    uint4 ua;
    ua.x = pack2(a0.x, a0.y);
    ua.y = pack2(a0.z, a0.w);
    ua.z = pack2(a1.x, a1.y);
    ua.w = pack2(a1.z, a1.w);
    *(uint4*)(&smem[row * 256 + s * 8]) = ua;
  }
  __syncthreads();

  f32x4 outacc[16];
#pragma unroll
  for (int i = 0; i < 16; i++) outacc[i] = zero4;

#pragma unroll
  for (int ks = 0; ks < 8; ++ks) {
    int sa = lo + 16 * ((quad & 1) * 2);
    unsigned int xA = (unsigned int)__shfl((int)c2[2 * ks].x, sa);
    unsigned int yA = (unsigned int)__shfl((int)c2[2 * ks].y, sa);
    unsigned int xB = (unsigned int)__shfl((int)c2[2 * ks].x, sa + 16);
    unsigned int yB = (unsigned int)__shfl((int)c2[2 * ks].y, sa + 16);
    unsigned int xA1 = (unsigned int)__shfl((int)c2[2 * ks + 1].x, sa);
    unsigned int yA1 = (unsigned int)__shfl((int)c2[2 * ks + 1].y, sa);
    unsigned int xB1 = (unsigned int)__shfl((int)c2[2 * ks + 1].x, sa + 16);
    unsigned int yB1 = (unsigned int)__shfl((int)c2[2 * ks + 1].y, sa + 16);
    union {
      unsigned int u[4];
      bf16x8 v;
    } cvt;
    bool hiq = (quad >> 1) != 0;
    cvt.u[0] = hiq ? xA1 : xA;
    cvt.u[1] = hiq ? yA1 : yA;
    cvt.u[2] = hiq ? xB1 : xB;
    cvt.u[3] = hiq ? yB1 : yB;
    bf16x8 pf = cvt.v;

    const int c = ks * 4 + quad;
    const int jj = (c & 24) | ((c ^ (lo & 7)) & 7);
    __builtin_amdgcn_s_setprio(1);
#pragma unroll
    for (int et = 0; et < 16; ++et) {
      bf16x8 af = *(const bf16x8*)(&smem[(et * 16 + lo) * 256 + jj * 8]);
      outacc[et] = MFMA16(af, pf, outacc[et]);
    }
    __builtin_amdgcn_s_setprio(0);
  }

  float* op = out + (size_t)qrow * 256;
#pragma unroll
  for (int et = 0; et < 16; ++et) {
    const float4 b4 = *(const float4*)(bias + et * 16 + quad * 4);
    float4 v;
    v.x = outacc[et][0] + b4.x;
    v.y = outacc[et][1] + b4.y;
    v.z = outacc[et][2] + b4.z;
    v.w = outacc[et][3] + b4.w;
    *(float4*)(op + et * 16 + quad * 4) = v;
  }
}

extern "C" void kernel_launch(void* const* d_in, const int* in_sizes, int n_in,
                              void* d_out, int out_size, void* d_ws, size_t ws_size,
                              hipStream_t stream) {
  const float* X = (const float*)d_in[0];
  const float* Wq = (const float*)d_in[1];
  const float* Wo = (const float*)d_in[2];
  const float* Bo = (const float*)d_in[3];
  float* out = (float*)d_out;
  unsigned short* ws = (unsigned short*)d_ws;

  const size_t NE = (size_t)16 * 2048 * 256;
  unsigned short* Qb = ws;
  unsigned short* Kb = ws + NE;
  unsigned short* Vt = ws + 2 * NE;
  unsigned short* Wqbf = (unsigned short*)d_out;  // dead until attn writes out

  cvtw_kernel<<<dim3(96), 256, 0, stream>>>(Wq, Wqbf);
  qkv_kernel<<<dim3(512), 256, 0, stream>>>(X, Wqbf, Qb, Kb, Vt);
  attn_kernel<<<dim3(256), 512, 0, stream>>>(Qb, Kb, Vt, Wo, Bo, out);
}